// Round 7
// baseline (243.961 us; speedup 1.0000x reference)
//
#include <hip/hip_runtime.h>
#include <hip/hip_cooperative_groups.h>
#include <math.h>

namespace cg = cooperative_groups;

#define EPS_F 1e-6f

// ---- workspace layout (float offsets), ~14 MB ----
#define OFF_WCQ 0                          // folded q weights [256][256]
#define OFF_WCK (OFF_WCQ + 65536)          // folded k weights [256][256]
#define OFF_BV  (OFF_WCK + 65536)          // folded v bias [256]
#define OFF_VC  (OFF_BV + 256)             // dwconv output [256][4096]
#define OFF_PS  (OFF_VC + 256*4096)        // partial Sm [8 h][64 chunk][64][64]
#define OFF_PSV (OFF_PS + 8*64*4096)       // partial sv [8 h][64 chunk][64]
#define OFF_SM  (OFF_PSV + 8*64*64)        // Sm [8][4096]
#define OFF_SV  (OFF_SM + 8*4096)          // sv [8][64]

struct P {
    const float *x, *Wv, *Wq, *Wk, *Wmq, *Wmk, *Wmv, *bmv, *bv, *bmk, *bmq;
    float *ws, *out;
};

// ---- Phase 0 (b in 0..255): fold hedgehog into q/k weights (row b) + dwconv
// for channel b (whole channel staged in LDS). R5-verified math.
__device__ __forceinline__ void phase0(int b, int t, float* smem, const P& p)
{
    int h = b >> 6, e = b & 63;
    float aq = 0.f, ak = 0.f;
    for (int d = 0; d < 64; ++d) {
        float mq = p.Wmq[e*64 + d];
        float mk = p.Wmk[e*64 + d];
        int src = (h*64 + d)*256 + t;
        aq = fmaf(mq, p.Wq[src], aq);
        ak = fmaf(mk, p.Wk[src], ak);
    }
    p.ws[OFF_WCQ + b*256 + t] = aq;
    p.ws[OFF_WCK + b*256 + t] = ak;
    if (t == 0) {
        float av = 0.f;
        for (int d = 0; d < 64; ++d) av = fmaf(p.Wmv[e*64 + d], p.bv[h*64 + d], av);
        p.ws[OFF_BV + b] = av + p.bmv[e];
    }
    // depthwise 3x3x3 conv, channel b
    const float* xc = p.x + (size_t)b*4096;
    #pragma unroll
    for (int i = 0; i < 16; ++i) smem[i*256 + t] = xc[i*256 + t];
    __syncthreads();
    int y = t >> 4, xx = t & 15;
    const float* wc = p.Wv + b*27;      // block-uniform -> scalar loads
    float w[27];
    #pragma unroll
    for (int i = 0; i < 27; ++i) w[i] = wc[i];
    for (int z = 0; z < 16; ++z) {
        float acc = 0.f;
        #pragma unroll
        for (int kz = 0; kz < 3; ++kz) {
            int zz = z + kz - 1;
            if (zz < 0 || zz > 15) continue;        // wave-uniform
            #pragma unroll
            for (int ky = 0; ky < 3; ++ky) {
                int yy = y + ky - 1;
                bool vy = (yy >= 0) && (yy < 16);
                int yc = yy < 0 ? 0 : (yy > 15 ? 15 : yy);
                #pragma unroll
                for (int kx = 0; kx < 3; ++kx) {
                    int xv = xx + kx - 1;
                    bool v = vy && (xv >= 0) && (xv < 16);
                    int xc2 = xv < 0 ? 0 : (xv > 15 ? 15 : xv);
                    float val = smem[zz*256 + yc*16 + xc2];
                    acc = fmaf(w[(kz*3 + ky)*3 + kx], v ? val : 0.f, acc);
                }
            }
        }
        p.ws[OFF_VC + (size_t)b*4096 + z*256 + t] = acc;
    }
    __syncthreads();
}

// ---- Phase 1 (b -> hb=b>>6, chunk=b&63): K-proj GEMM (K=256) + V-proj
// (K=64 block-diag) -> exp± in LDS -> outer products -> partials. R2-verified.
__device__ __forceinline__ void phase1(int b, int t, float* smem, const P& p)
{
    float* Xs  = smem;              // [64][64]
    float* Wsh = smem + 4096;       // [64][68]
    float* kfp = smem;              // [64][64] overlays, barrier-separated
    float* kfm = smem + 4096;
    float* vfp = smem + 8192;
    float* vfm = smem + 12288;
    float* ws = p.ws;

    int hb = b >> 6, chunk = b & 63;
    int n0 = chunk * 64;
    int lc = t >> 6, ln = t & 63;
    int e4 = (t & 15) * 4;
    int n4 = (t >> 4) * 4;

    float accK[4][4], accV[4][4];
    #pragma unroll
    for (int i = 0; i < 4; ++i)
        #pragma unroll
        for (int j = 0; j < 4; ++j) { accK[i][j] = 0.f; accV[i][j] = 0.f; }

    const float* Wck = ws + OFF_WCK;
    for (int c0 = 0; c0 < 256; c0 += 64) {
        #pragma unroll
        for (int i = 0; i < 16; ++i)
            Xs[(lc*16 + i)*64 + ln] = p.x[(size_t)(c0 + lc*16 + i)*4096 + n0 + ln];
        #pragma unroll
        for (int i = 0; i < 16; ++i)
            Wsh[ln*68 + lc*16 + i] = Wck[(size_t)(hb*64 + lc*16 + i)*256 + c0 + ln];
        __syncthreads();
        #pragma unroll 4
        for (int c = 0; c < 64; ++c) {
            float4 xv4 = *(const float4*)&Xs[c*64 + n4];
            float4 wv4 = *(const float4*)&Wsh[c*68 + e4];
            float xv[4] = {xv4.x, xv4.y, xv4.z, xv4.w};
            float wv[4] = {wv4.x, wv4.y, wv4.z, wv4.w};
            #pragma unroll
            for (int ii = 0; ii < 4; ++ii)
                #pragma unroll
                for (int jj = 0; jj < 4; ++jj)
                    accK[ii][jj] = fmaf(xv[ii], wv[jj], accK[ii][jj]);
        }
        __syncthreads();
    }
    {
        const float* vcb = ws + OFF_VC + (size_t)hb*64*4096;
        #pragma unroll
        for (int i = 0; i < 16; ++i)
            Xs[(lc*16 + i)*64 + ln] = vcb[(size_t)(lc*16 + i)*4096 + n0 + ln];
        #pragma unroll
        for (int i = 0; i < 16; ++i) {
            int idx = i*256 + t, dd = idx & 63, ee = idx >> 6;
            Wsh[dd*68 + ee] = p.Wmv[ee*64 + dd];
        }
        __syncthreads();
        #pragma unroll 4
        for (int d = 0; d < 64; ++d) {
            float4 xv4 = *(const float4*)&Xs[d*64 + n4];
            float4 wv4 = *(const float4*)&Wsh[d*68 + e4];
            float xv[4] = {xv4.x, xv4.y, xv4.z, xv4.w};
            float wv[4] = {wv4.x, wv4.y, wv4.z, wv4.w};
            #pragma unroll
            for (int ii = 0; ii < 4; ++ii)
                #pragma unroll
                for (int jj = 0; jj < 4; ++jj)
                    accV[ii][jj] = fmaf(xv[ii], wv[jj], accV[ii][jj]);
        }
        __syncthreads();
    }
    float bk[4], bvv[4];
    #pragma unroll
    for (int j = 0; j < 4; ++j) { bk[j] = p.bmk[e4 + j]; bvv[j] = ws[OFF_BV + hb*64 + e4 + j]; }
    #pragma unroll
    for (int ii = 0; ii < 4; ++ii) {
        float pk[4], mk_[4], pv[4], mv[4];
        #pragma unroll
        for (int jj = 0; jj < 4; ++jj) {
            float a = accK[ii][jj] + bk[jj];
            pk[jj] = __expf(a);  mk_[jj] = __expf(-a);
            float bb = accV[ii][jj] + bvv[jj];
            pv[jj] = __expf(bb);  mv[jj] = __expf(-bb);
        }
        int r = (n4 + ii)*64 + e4;
        *(float4*)&kfp[r] = make_float4(pk[0], pk[1], pk[2], pk[3]);
        *(float4*)&kfm[r] = make_float4(mk_[0], mk_[1], mk_[2], mk_[3]);
        *(float4*)&vfp[r] = make_float4(pv[0], pv[1], pv[2], pv[3]);
        *(float4*)&vfm[r] = make_float4(mv[0], mv[1], mv[2], mv[3]);
    }
    __syncthreads();
    int a4 = e4, f4 = n4;
    float aSp[4][4], aSm[4][4], svp[4], svm[4];
    #pragma unroll
    for (int i = 0; i < 4; ++i) {
        svp[i] = 0.f; svm[i] = 0.f;
        #pragma unroll
        for (int j = 0; j < 4; ++j) { aSp[i][j] = 0.f; aSm[i][j] = 0.f; }
    }
    #pragma unroll 2
    for (int n = 0; n < 64; ++n) {
        float4 kp4 = *(const float4*)&kfp[n*64 + a4];
        float4 km4 = *(const float4*)&kfm[n*64 + a4];
        float4 vp4 = *(const float4*)&vfp[n*64 + f4];
        float4 vm4 = *(const float4*)&vfm[n*64 + f4];
        float kp[4] = {kp4.x, kp4.y, kp4.z, kp4.w};
        float km[4] = {km4.x, km4.y, km4.z, km4.w};
        float vp[4] = {vp4.x, vp4.y, vp4.z, vp4.w};
        float vm[4] = {vm4.x, vm4.y, vm4.z, vm4.w};
        #pragma unroll
        for (int ai = 0; ai < 4; ++ai) {
            svp[ai] += kp[ai];  svm[ai] += km[ai];
            #pragma unroll
            for (int fi = 0; fi < 4; ++fi) {
                aSp[ai][fi] = fmaf(kp[ai], vp[fi], aSp[ai][fi]);
                aSm[ai][fi] = fmaf(km[ai], vm[fi], aSm[ai][fi]);
            }
        }
    }
    float* pSp = ws + OFF_PS + (size_t)(hb*64 + chunk)*4096;
    float* pSm = ws + OFF_PS + (size_t)((hb + 4)*64 + chunk)*4096;
    #pragma unroll
    for (int ai = 0; ai < 4; ++ai) {
        *(float4*)&pSp[(a4 + ai)*64 + f4] = make_float4(aSp[ai][0], aSp[ai][1], aSp[ai][2], aSp[ai][3]);
        *(float4*)&pSm[(a4 + ai)*64 + f4] = make_float4(aSm[ai][0], aSm[ai][1], aSm[ai][2], aSm[ai][3]);
    }
    if (t < 16) {
        float* pvp = ws + OFF_PSV + (size_t)(hb*64 + chunk)*64;
        float* pvm = ws + OFF_PSV + (size_t)((hb + 4)*64 + chunk)*64;
        *(float4*)&pvp[a4] = make_float4(svp[0], svp[1], svp[2], svp[3]);
        *(float4*)&pvm[a4] = make_float4(svm[0], svm[1], svm[2], svm[3]);
    }
    __syncthreads();
}

// ---- Phase 2: reduce 64-chunk partials (gid-ranged, any over-provision OK)
__device__ __forceinline__ void phase2(int b, int t, const P& p)
{
    float* ws = p.ws;
    int gid = b*256 + t;
    if (gid < 8*4096) {
        int h = gid >> 12, r = gid & 4095;
        float s = 0.f;
        #pragma unroll 16
        for (int c = 0; c < 64; ++c) s += ws[OFF_PS + (size_t)(h*64 + c)*4096 + r];
        ws[OFF_SM + gid] = s;
    } else if (gid < 8*4096 + 512) {
        int j = gid - 8*4096;
        int h = j >> 6, e = j & 63;
        float s = 0.f;
        #pragma unroll 16
        for (int c = 0; c < 64; ++c) s += ws[OFF_PSV + (size_t)(h*64 + c)*64 + e];
        ws[OFF_SV + j] = s;
    }
}

// ---- Phase 3 (b -> hb, chunk): Q-proj GEMM -> qf± transposed [a][n] in LDS ->
// out = (qf·Sm)/(qf·sv + eps) for heads hb, hb+4. R2-verified.
__device__ __forceinline__ void phase3(int b, int t, float* smem, const P& p)
{
    float* Xs   = smem;             // [64][64]
    float* Wsh  = smem + 4096;      // [64][68]
    float* qfTp = smem;             // [a][n] overlays
    float* qfTm = smem + 4096;
    float* Sms  = smem + 8192;      // [64][64]
    float* svs  = smem + 12288;     // [64]
    float* ws = p.ws;

    int hb = b >> 6, chunk = b & 63;
    int n0 = chunk * 64;
    int lc = t >> 6, ln = t & 63;
    int a4 = (t & 15) * 4;
    int n4 = (t >> 4) * 4;

    float accQ[4][4];               // [n][e]
    #pragma unroll
    for (int i = 0; i < 4; ++i)
        #pragma unroll
        for (int j = 0; j < 4; ++j) accQ[i][j] = 0.f;

    const float* Wcq = ws + OFF_WCQ;
    for (int c0 = 0; c0 < 256; c0 += 64) {
        #pragma unroll
        for (int i = 0; i < 16; ++i)
            Xs[(lc*16 + i)*64 + ln] = p.x[(size_t)(c0 + lc*16 + i)*4096 + n0 + ln];
        #pragma unroll
        for (int i = 0; i < 16; ++i)
            Wsh[ln*68 + lc*16 + i] = Wcq[(size_t)(hb*64 + lc*16 + i)*256 + c0 + ln];
        __syncthreads();
        #pragma unroll 4
        for (int c = 0; c < 64; ++c) {
            float4 xv4 = *(const float4*)&Xs[c*64 + n4];
            float4 wv4 = *(const float4*)&Wsh[c*68 + a4];
            float xv[4] = {xv4.x, xv4.y, xv4.z, xv4.w};
            float wv[4] = {wv4.x, wv4.y, wv4.z, wv4.w};
            #pragma unroll
            for (int ii = 0; ii < 4; ++ii)
                #pragma unroll
                for (int jj = 0; jj < 4; ++jj)
                    accQ[ii][jj] = fmaf(xv[ii], wv[jj], accQ[ii][jj]);
        }
        __syncthreads();
    }
    #pragma unroll
    for (int jj = 0; jj < 4; ++jj) {
        float bq = p.bmq[a4 + jj];
        float v0 = accQ[0][jj] + bq, v1 = accQ[1][jj] + bq,
              v2 = accQ[2][jj] + bq, v3 = accQ[3][jj] + bq;
        *(float4*)&qfTp[(a4 + jj)*64 + n4] =
            make_float4(__expf(v0), __expf(v1), __expf(v2), __expf(v3));
        *(float4*)&qfTm[(a4 + jj)*64 + n4] =
            make_float4(__expf(-v0), __expf(-v1), __expf(-v2), __expf(-v3));
    }

    int n4b = (t & 15) * 4;
    int e4b = (t >> 4) * 4;
    for (int s = 0; s < 2; ++s) {
        int h = hb + 4*s;
        __syncthreads();
        const float* Smg = ws + OFF_SM + (size_t)h*4096;
        #pragma unroll
        for (int i = 0; i < 16; ++i) { int idx = i*256 + t; Sms[idx] = Smg[idx]; }
        if (t < 64) svs[t] = ws[OFF_SV + h*64 + t];
        __syncthreads();

        const float* qf = s ? qfTm : qfTp;
        float acc[4][4];            // [e][n]
        float den[4] = {0.f, 0.f, 0.f, 0.f};
        #pragma unroll
        for (int i = 0; i < 4; ++i)
            #pragma unroll
            for (int j = 0; j < 4; ++j) acc[i][j] = 0.f;
        #pragma unroll 4
        for (int a = 0; a < 64; ++a) {
            float4 qv4 = *(const float4*)&qf[a*64 + n4b];
            float4 sm4 = *(const float4*)&Sms[a*64 + e4b];
            float qv[4] = {qv4.x, qv4.y, qv4.z, qv4.w};
            float sm[4] = {sm4.x, sm4.y, sm4.z, sm4.w};
            float sva = svs[a];
            #pragma unroll
            for (int nj = 0; nj < 4; ++nj) {
                den[nj] = fmaf(qv[nj], sva, den[nj]);
                #pragma unroll
                for (int ei = 0; ei < 4; ++ei)
                    acc[ei][nj] = fmaf(sm[ei], qv[nj], acc[ei][nj]);
            }
        }
        float r[4];
        #pragma unroll
        for (int nj = 0; nj < 4; ++nj) r[nj] = 1.f / (den[nj] + EPS_F);
        #pragma unroll
        for (int ei = 0; ei < 4; ++ei)
            *(float4*)&p.out[(size_t)(h*64 + e4b + ei)*4096 + n0 + n4b] =
                make_float4(acc[ei][0]*r[0], acc[ei][1]*r[1], acc[ei][2]*r[2], acc[ei][3]*r[3]);
    }
}

// ---- single cooperative kernel: 256 blocks (1/CU -> always schedulable) ----
__global__ __launch_bounds__(256) void k_mega(P p)
{
    cg::grid_group grid = cg::this_grid();
    __shared__ float smem[16384];
    int b = blockIdx.x, t = threadIdx.x;
    phase0(b, t, smem, p);
    grid.sync();
    phase1(b, t, smem, p);
    grid.sync();
    phase2(b, t, p);
    grid.sync();
    phase3(b, t, smem, p);
}

// ---- fallback wrappers (same phase bodies, classic launches) ----
__global__ __launch_bounds__(256) void k_p0(P p) { __shared__ float smem[16384]; phase0(blockIdx.x, threadIdx.x, smem, p); }
__global__ __launch_bounds__(256) void k_p1(P p) { __shared__ float smem[16384]; phase1(blockIdx.x, threadIdx.x, smem, p); }
__global__ __launch_bounds__(256) void k_p2(P p) { phase2(blockIdx.x, threadIdx.x, p); }
__global__ __launch_bounds__(256) void k_p3(P p) { __shared__ float smem[16384]; phase3(blockIdx.x, threadIdx.x, smem, p); }

extern "C" void kernel_launch(void* const* d_in, const int* in_sizes, int n_in,
                              void* d_out, int out_size, void* d_ws, size_t ws_size,
                              hipStream_t stream) {
    P p;
    p.x   = (const float*)d_in[0];
    p.Wq  = (const float*)d_in[1];
    p.Wk  = (const float*)d_in[2];
    p.Wv  = (const float*)d_in[3];
    p.bv  = (const float*)d_in[4];
    p.Wmq = (const float*)d_in[5];
    p.bmq = (const float*)d_in[6];
    p.Wmk = (const float*)d_in[7];
    p.bmk = (const float*)d_in[8];
    p.Wmv = (const float*)d_in[9];
    p.bmv = (const float*)d_in[10];
    p.out = (float*)d_out;
    p.ws  = (float*)d_ws;

    void* args[] = { (void*)&p };
    hipError_t err = hipLaunchCooperativeKernel((const void*)k_mega, dim3(256),
                                                dim3(256), args, 0, stream);
    if (err != hipSuccess) {
        // deterministic fallback: identical phase bodies, 4 classic launches
        k_p0<<<256, 256, 0, stream>>>(p);
        k_p1<<<256, 256, 0, stream>>>(p);
        k_p2<<<130, 256, 0, stream>>>(p);
        k_p3<<<256, 256, 0, stream>>>(p);
    }
}